// Round 6
// baseline (297.593 us; speedup 1.0000x reference)
//
#include <hip/hip_runtime.h>
#include <math.h>

#define DEV_EPS 1e-5f

namespace {
constexpr int B_ = 16, C_ = 256, H_ = 56, W_ = 56, HW_ = H_ * W_;
constexpr int G_ = 16, GC_ = 16, RED_ = 64, KK_ = 49;
constexpr int NTOT = B_ * HW_;  // 50176 flattened (batch, pixel)

typedef __attribute__((ext_vector_type(8))) short short8;
typedef __attribute__((ext_vector_type(4))) float f32x4;

__device__ __forceinline__ unsigned short bf16r(float f) {
  unsigned u = __float_as_uint(f);
  u += 0x7fff + ((u >> 16) & 1);  // RNE
  return (unsigned short)(u >> 16);
}
__device__ __forceinline__ float bf2f(unsigned short s) {
  return __uint_as_float((unsigned)s << 16);
}

// tanh(x) = sign(x)*(1-e)/(1+e), e = exp(-2|x|).  ~8 VALU ops vs ~25 OCML.
__device__ __forceinline__ float fast_tanh(float x) {
  float ax = fabsf(x);
  float e = __expf(-2.0f * ax);
  float r = (1.0f - e) * __builtin_amdgcn_rcpf(1.0f + e);
  return copysignf(r, x);
}

// async global->LDS, 16B per lane (wave-uniform LDS base + lane*16, m104).
__device__ __forceinline__ void gl_lds16(const void* g, void* l) {
  __builtin_amdgcn_global_load_lds(
      (const __attribute__((address_space(1))) unsigned int*)g,
      (__attribute__((address_space(3))) unsigned int*)l, 16, 0, 0);
}

// ---------------------------------------------------------------------------
// gemm_yr (unchanged from v10):  y_T = tanh(bn1(w1 @ x));  r_T = relu(bnr(.))
// x-transpose fused (regs -> cvt -> swizzled ds_write), A-frags from global,
// T3-min 2-phase Bt dbuf.
// ---------------------------------------------------------------------------
constexpr int YS_STR = 264;  // ushort stride for yS [64 px][256 ch + 8 pad]

__global__ __launch_bounds__(256)
void gemm_yr(const unsigned short* __restrict__ A,     // w1b [256][256]
             const float* __restrict__ x,              // planar fp32
             const unsigned short* __restrict__ redw,  // redb [64][256]
             const float* __restrict__ p0,             // b1
             const float* __restrict__ bg, const float* __restrict__ bb,
             const float* __restrict__ bm, const float* __restrict__ bv,
             const float* __restrict__ rp0,            // red_b
             const float* __restrict__ rbg, const float* __restrict__ rbb,
             const float* __restrict__ rbm, const float* __restrict__ rbv,
             unsigned short* __restrict__ yT, unsigned short* __restrict__ rT) {
  __shared__ __align__(16) unsigned short blob2[16896];  // 33792 B
  __shared__ float aS[256], bS[256], aR[64], bR[64];
  unsigned short* Bt0 = blob2;         // [64][64]
  unsigned short* Bt1 = blob2 + 4096;  // [64][64]
  unsigned short* yS = blob2;          // [64][YS_STR] alias after loop

  const int tid = threadIdx.x;
  const int n0 = blockIdx.x * 64;           // 64-px tile; HW%64==0 -> same b
  const int bi = n0 / HW_, hw0 = n0 - bi * HW_;
  const int wave = tid >> 6, lane = tid & 63;
  const int quad = lane >> 4, ln = lane & 15;
  const int c2 = tid >> 3, pxo = tid & 7;   // ch-pair, px-octet for transpose

  {
    float sc = bg[tid] * rsqrtf(bv[tid] + DEV_EPS);
    aS[tid] = sc;
    bS[tid] = sc * p0[tid] + bb[tid] - bm[tid] * sc;
    if (tid < 64) {
      float s2 = rbg[tid] * rsqrtf(rbv[tid] + DEV_EPS);
      aR[tid] = s2;
      bR[tid] = s2 * rp0[tid] + rbb[tid] - rbm[tid] * s2;
    }
  }

  float4 xa, xb, xc, xd;  // 2 channels x 8 px fp32, in flight across compute
  auto load_x = [&](int kt) {
    const float* p = x + ((size_t)bi * C_ + kt * 64 + 2 * c2) * HW_ + hw0 + pxo * 8;
    xa = *(const float4*)p;
    xb = *(const float4*)(p + 4);
    xc = *(const float4*)(p + HW_);
    xd = *(const float4*)(p + HW_ + 4);
  };
  auto commit_x = [&](unsigned short* bt) {
    float e0[8] = {xa.x, xa.y, xa.z, xa.w, xb.x, xb.y, xb.z, xb.w};
    float e1[8] = {xc.x, xc.y, xc.z, xc.w, xd.x, xd.y, xd.z, xd.w};
    const int kc = c2 >> 2;          // k-chunk of this channel pair
    const int off = 2 * (c2 & 3);    // within-chunk ushort offset (even)
#pragma unroll
    for (int i = 0; i < 8; ++i) {
      int pxl = pxo * 8 + i;
      int slot = kc ^ (i & 7);       // pxl&7 == i (pxo*8 is 8-aligned)
      unsigned pk = (unsigned)bf16r(e0[i]) | ((unsigned)bf16r(e1[i]) << 16);
      *(unsigned*)&bt[pxl * 64 + slot * 8 + off] = pk;
    }
  };

  f32x4 acc[4][4];
#pragma unroll
  for (int i = 0; i < 4; ++i)
#pragma unroll
    for (int j = 0; j < 4; ++j)
#pragma unroll
      for (int e = 0; e < 4; ++e) acc[i][j][e] = 0.f;

  load_x(0);
  commit_x(Bt0);
  __syncthreads();

#pragma unroll 1
  for (int kt = 0; kt < 4; ++kt) {
    unsigned short* cur = (kt & 1) ? Bt1 : Bt0;
    unsigned short* nxt = (kt & 1) ? Bt0 : Bt1;
    if (kt < 3) load_x(kt + 1);  // in flight during compute (T3-min)
#pragma unroll
    for (int s = 0; s < 2; ++s) {
      const int c = s * 4 + quad;
      short8 af[4], bf[4];
#pragma unroll
      for (int i = 0; i < 4; ++i)
        af[i] = *(const short8*)&A[(size_t)(wave * 64 + i * 16 + ln) * 256 +
                                   kt * 64 + c * 8];
#pragma unroll
      for (int j = 0; j < 4; ++j) {
        int r = j * 16 + ln;
        bf[j] = *(const short8*)&cur[r * 64 + (c ^ (r & 7)) * 8];
      }
#pragma unroll
      for (int i = 0; i < 4; ++i)
#pragma unroll
        for (int j = 0; j < 4; ++j)
          acc[i][j] = __builtin_amdgcn_mfma_f32_16x16x32_bf16(af[i], bf[j],
                                                              acc[i][j], 0, 0, 0);
    }
    if (kt < 3) commit_x(nxt);  // cvt+ds_write after compute (latency hidden)
    __syncthreads();
  }

  // y epilogue: tanh(bn1) -> yT (global) + yS (LDS, [px][ch])
#pragma unroll
  for (int i = 0; i < 4; ++i) {
    const int mloc = wave * 64 + i * 16 + quad * 4;
#pragma unroll
    for (int j = 0; j < 4; ++j) {
      const int npl = j * 16 + ln;
      ushort4 pk;
      unsigned short* pp = (unsigned short*)&pk;
#pragma unroll
      for (int r = 0; r < 4; ++r) {
        float v = aS[mloc + r] * acc[i][j][r] + bS[mloc + r];
        pp[r] = bf16r(fast_tanh(v));
      }
      *(ushort4*)(yT + (size_t)(n0 + npl) * 256 + mloc) = pk;
      *(ushort4*)(yS + npl * YS_STR + mloc) = pk;
    }
  }
  __syncthreads();  // yS complete

  // RED GEMM: r[64][64px] = redw(64x256) @ yS^T ; A-frags from global (L2)
  f32x4 acc2[4];
#pragma unroll
  for (int j = 0; j < 4; ++j)
#pragma unroll
    for (int e = 0; e < 4; ++e) acc2[j][e] = 0.f;
#pragma unroll
  for (int kc = 0; kc < 8; ++kc) {
    short8 af2 =
        *(const short8*)&redw[(size_t)(wave * 16 + ln) * 256 + kc * 32 + quad * 8];
#pragma unroll
    for (int j = 0; j < 4; ++j) {
      short8 bf2 = *(const short8*)&yS[(j * 16 + ln) * YS_STR + kc * 32 + quad * 8];
      acc2[j] = __builtin_amdgcn_mfma_f32_16x16x32_bf16(af2, bf2, acc2[j], 0, 0, 0);
    }
  }
  {
    const int m2 = wave * 16 + quad * 4;
#pragma unroll
    for (int j = 0; j < 4; ++j) {
      const int np = n0 + j * 16 + ln;
      ushort4 pk;
      unsigned short* pp = (unsigned short*)&pk;
#pragma unroll
      for (int r = 0; r < 4; ++r) {
        float v = aR[m2 + r] * acc2[j][r] + bR[m2 + r];
        pp[r] = bf16r(fmaxf(v, 0.f));
      }
      *(ushort4*)(rT + (size_t)np * 64 + m2) = pk;
    }
  }
}

// ---------------------------------------------------------------------------
// gemm_out v2: LDS-FREE streaming register GEMM.
//  K=256 is thin: LDS staging bought only 2x within-block B-reuse but cost
//  4 barriers + vmcnt(0) drains + a ~250cyc post-barrier A-load stall per kt.
//  Now BOTH A (w3b) and B (tT) fragments are per-lane short8 global loads;
//  zero K-loop barriers -> compiler software-pipelines all 64 loads against
//  128 MFMAs across the fully-unrolled K.  Extra L2/L3 traffic (~2x tT,
//  ~25 MB) is noise at 34 TB/s.  LDS = 1 KB (bn params) -> occupancy is
//  VGPR-bound only.
// ---------------------------------------------------------------------------
__global__ __launch_bounds__(256)
void gemm_out(const unsigned short* __restrict__ A,    // w3b [256][256]
              const unsigned short* __restrict__ Act,  // tT [NTOT][256]
              const float* __restrict__ p0,
              const float* __restrict__ bg, const float* __restrict__ bb,
              const float* __restrict__ bm, const float* __restrict__ bv,
              const float* __restrict__ xskip, float* __restrict__ out) {
  __shared__ float aS[128], bS[128];

  const int tid = threadIdx.x;
  const int n0 = blockIdx.x * 128, m0 = blockIdx.y * 128;
  const int wave = tid >> 6, lane = tid & 63;
  const int wm = wave >> 1, wn = wave & 1;
  const int quad = lane >> 4, ln = lane & 15;

  if (tid < 128) {
    int m = m0 + tid;
    float sc = bg[m] * rsqrtf(bv[m] + DEV_EPS);
    aS[tid] = sc;
    bS[tid] = sc * p0[m] + bb[m] - bm[m] * sc;
  }
  __syncthreads();  // the only barrier

  f32x4 acc[4][4];
#pragma unroll
  for (int i = 0; i < 4; ++i)
#pragma unroll
    for (int j = 0; j < 4; ++j)
#pragma unroll
      for (int e = 0; e < 4; ++e) acc[i][j][e] = 0.f;

  const unsigned short* Abase = A + (size_t)(m0 + wm * 64 + ln) * 256;
  const unsigned short* Bbase = Act + (size_t)(n0 + wn * 64 + ln) * 256;

#pragma unroll
  for (int kt = 0; kt < 4; ++kt) {
#pragma unroll
    for (int s = 0; s < 2; ++s) {
      const int ko = kt * 64 + (s * 4 + quad) * 8;
      short8 af[4], bf[4];
#pragma unroll
      for (int i = 0; i < 4; ++i)
        af[i] = *(const short8*)&Abase[(size_t)(i * 16) * 256 + ko];
#pragma unroll
      for (int j = 0; j < 4; ++j)
        bf[j] = *(const short8*)&Bbase[(size_t)(j * 16) * 256 + ko];
#pragma unroll
      for (int i = 0; i < 4; ++i)
#pragma unroll
        for (int j = 0; j < 4; ++j)
          acc[i][j] = __builtin_amdgcn_mfma_f32_16x16x32_bf16(af[i], bf[j],
                                                              acc[i][j], 0, 0, 0);
    }
  }

  // epilogue: bn3 + x skip -> planar fp32
#pragma unroll
  for (int i = 0; i < 4; ++i) {
    const int mloc = wm * 64 + i * 16 + quad * 4;
#pragma unroll
    for (int j = 0; j < 4; ++j) {
      const int np = n0 + wn * 64 + j * 16 + ln;
      int b = np / HW_, hw = np - b * HW_;
      size_t base = ((size_t)b * C_ + m0 + mloc) * HW_ + hw;
#pragma unroll
      for (int r = 0; r < 4; ++r) {
        size_t o = base + (size_t)r * HW_;
        out[o] = aS[mloc + r] * acc[i][j][r] + bS[mloc + r] + xskip[o];
      }
    }
  }
}

// weights fp32 -> bf16 (all four mats)
__global__ __launch_bounds__(256)
void wconv(const float* __restrict__ w1, const float* __restrict__ rw,
           const float* __restrict__ sw, const float* __restrict__ w3,
           unsigned short* __restrict__ o1, unsigned short* __restrict__ orw,
           unsigned short* __restrict__ osw, unsigned short* __restrict__ ow3) {
  int i = blockIdx.x * 256 + threadIdx.x;
  if (i < 65536) o1[i] = bf16r(w1[i]);
  if (i < 16384) orw[i] = bf16r(rw[i]);
  if (i < 50176) osw[i] = bf16r(sw[i]);
  if (i < 65536) ow3[i] = bf16r(w3[i]);
}

// ---------------------------------------------------------------------------
// Gather v9 (unchanged): span GEMM fused; bf16 patch; aliased 51 KB blob
// (3 blocks/CU); T14 patch prefetch; g-fastest grid; fast_tanh; phase-D
// gc-pair weight sharing.
// ---------------------------------------------------------------------------
constexpr int PB_STR = 648;     // ushort patch plane stride (640 used + 8 pad)
constexpr int W_TAP_STR = 232;  // ushort: 224 px + 8 pad
constexpr int BLOB_N = 25320;   // 50640 B

__global__ __launch_bounds__(256)
void gather_inv(const unsigned short* __restrict__ yT,
                const unsigned short* __restrict__ rT,
                const unsigned short* __restrict__ spanw,  // [784][64] bf16
                const float* __restrict__ spanb,           // [784] fp32
                const float* __restrict__ g2, const float* __restrict__ b2,
                const float* __restrict__ m2, const float* __restrict__ v2,
                unsigned short* __restrict__ tT) {
  __shared__ __align__(16) unsigned short blob[BLOB_N];
  __shared__ float a2s[16], b2s[16], sbs[KK_];

  unsigned short* rs = blob;            // 224*64 shorts (swizzled rows)
  unsigned short* sws = blob + 14336;   // 64*64 shorts (swizzled rows)
  unsigned short* patchb = blob;        // [16][PB_STR] bf16 planes
  unsigned short* wts = blob + 10368;   // [49][W_TAP_STR]
  unsigned short* tb = blob + 21736;    // [224][16]

  const int tid = threadIdx.x;
  const int g = blockIdx.x;   // g fastest: 16 blocks sharing rT stripe adjacent
  const int st = blockIdx.y;  // 4-row stripe 0..13
  const int b = blockIdx.z;
  const int h0 = st * 4;
  const int wave = tid >> 6, lane = tid & 63;
  const int lq = lane & 7, lr8 = lane >> 3;
  const int quad = lane >> 4, ln = lane & 15;

  // ---- phase 0: issue patch global loads to regs ----
  uint4 pv0[3], pv1[3];
  int poff[3];
  bool pok[3];
#pragma unroll
  for (int pi = 0; pi < 3; ++pi) {
    int e = tid + pi * 256;
    bool ok = e < 620;
    int row = e / 62, cw = e - row * 62;
    int sr = h0 + row - 3, sc = cw - 3;
    poff[pi] = row * 64 + cw;
    pok[pi] = ok;
    bool inb = ok && sr >= 0 && sr < H_ && sc >= 0 && sc < W_;
    if (inb) {
      const unsigned short* yp =
          yT + ((size_t)b * HW_ + sr * W_ + sc) * C_ + g * GC_;
      pv0[pi] = *(const uint4*)yp;
      pv1[pi] = *(const uint4*)(yp + 8);
    } else {
      pv0[pi] = make_uint4(0, 0, 0, 0);
      pv1[pi] = make_uint4(0, 0, 0, 0);
    }
  }

  // ---- phase A: stage rs (224x64) + sws (64x64) via global_load_lds ----
  {
    const unsigned short* rbase = rT + ((size_t)b * HW_ + h0 * W_) * RED_;
#pragma unroll
    for (int t = 0; t < 7; ++t) {
      int inst = wave * 7 + t;
      int row = inst * 8 + lr8;
      int qs = lq ^ (row & 7);
      gl_lds16(rbase + (size_t)row * RED_ + qs * 8, &rs[inst * 512]);
    }
    const unsigned short* swg = spanw + (size_t)(g * KK_) * RED_;
#pragma unroll
    for (int t = 0; t < 2; ++t) {
      int inst = wave * 2 + t;
      int row = inst * 8 + lr8;
      int tap = min(row, KK_ - 1);
      int qs = lq ^ (row & 7);
      gl_lds16(swg + (size_t)tap * RED_ + qs * 8, &sws[inst * 512]);
    }
    if (tid < 16) {
      int c = g * GC_ + tid;
      float sc = g2[c] * rsqrtf(v2[c] + DEV_EPS);
      a2s[tid] = sc;
      b2s[tid] = b2[c] - m2[c] * sc;
    }
    if (tid < KK_) sbs[tid] = spanb[g * KK_ + tid];
  }
  __syncthreads();  // drains vmcnt: rs/sws in LDS, patch regs loaded

  // ---- phase B: mini-MFMA  (wave = tap-tile) ----
  f32x4 wacc[14];
#pragma unroll
  for (int j = 0; j < 14; ++j)
#pragma unroll
    for (int e = 0; e < 4; ++e) wacc[j][e] = 0.f;
  {
    short8 af[2];
#pragma unroll
    for (int s = 0; s < 2; ++s) {
      int c = s * 4 + quad;
      int r = wave * 16 + ln;
      af[s] = *(const short8*)&sws[r * 64 + (c ^ (r & 7)) * 8];
    }
#pragma unroll
    for (int j = 0; j < 14; ++j) {
#pragma unroll
      for (int s = 0; s < 2; ++s) {
        int c = s * 4 + quad;
        int r = j * 16 + ln;
        short8 bf = *(const short8*)&rs[r * 64 + (c ^ (r & 7)) * 8];
        wacc[j] = __builtin_amdgcn_mfma_f32_16x16x32_bf16(af[s], bf, wacc[j],
                                                          0, 0, 0);
      }
    }
  }
  __syncthreads();  // frag reads done; rs/sws dead -> blob reusable

  // ---- phase C: write wts[tap][px] bf16 + patch bf16 planes ----
  {
#pragma unroll
    for (int r = 0; r < 4; ++r) {
      int tap = wave * 16 + quad * 4 + r;
      if (tap < KK_) {
        float sb = sbs[tap];
#pragma unroll
        for (int j = 0; j < 14; ++j)
          wts[tap * W_TAP_STR + j * 16 + ln] = bf16r(wacc[j][r] + sb);
      }
    }
#pragma unroll
    for (int pi = 0; pi < 3; ++pi) {
      if (pok[pi]) {
        int off = poff[pi];
        unsigned wv[8] = {pv0[pi].x, pv0[pi].y, pv0[pi].z, pv0[pi].w,
                          pv1[pi].x, pv1[pi].y, pv1[pi].z, pv1[pi].w};
#pragma unroll
        for (int cc = 0; cc < 8; ++cc) {
          patchb[(2 * cc) * PB_STR + off] = (unsigned short)wv[cc];
          patchb[(2 * cc + 1) * PB_STR + off] = (unsigned short)(wv[cc] >> 16);
        }
      }
    }
  }
  __syncthreads();

  // ---- phase D: 7x7 gather; item = (gc-pair, px4 strip) ----
#pragma unroll 1
  for (int it = 0; it < 2; ++it) {
    int item = tid + it * 256;
    if (item < 56 * 8) {
      const int gcp = item & 7, s = item >> 3;
      const int gc0 = gcp * 2;
      const int r0 = s / 14, c0 = (s - r0 * 14) * 4;
      const unsigned short* pg0 = patchb + gc0 * PB_STR + r0 * 64 + c0;
      const unsigned short* pg1 = pg0 + PB_STR;
      const unsigned short* wp = wts + (r0 * 56 + c0);
      float a00 = 0.f, a01 = 0.f, a02 = 0.f, a03 = 0.f;
      float a10 = 0.f, a11 = 0.f, a12 = 0.f, a13 = 0.f;
#pragma unroll
      for (int di = 0; di < 7; ++di) {
        const unsigned short* p0p = pg0 + di * 64;
        const unsigned short* p1p = pg1 + di * 64;
        uint2 q0 = *(const uint2*)p0p;
        uint2 q1 = *(const uint2*)(p0p + 4);
        uint2 q2 = *(const uint2*)(p0p + 8);
        uint2 u0 = *(const uint2*)p1p;
        uint2 u1 = *(const uint2*)(p1p + 4);
        uint2 u2 = *(const uint2*)(p1p + 8);
        unsigned uu0[6] = {q0.x, q0.y, q1.x, q1.y, q2.x, q2.y};
        unsigned uu1[6] = {u0.x, u0.y, u1.x, u1.y, u2.x, u2.y};
        float pf0[12], pf1[12];
#pragma unroll
        for (int k = 0; k < 6; ++k) {
          pf0[2 * k] = __uint_as_float(uu0[k] << 16);
          pf0[2 * k + 1] = __uint_as_float(uu0[k] & 0xffff0000u);
          pf1[2 * k] = __uint_as_float(uu1[k] << 16);
          pf1[2 * k + 1] = __uint_as_float(uu1[k] & 0xffff0000u);
        }
#pragma unroll
        for (int dj = 0; dj < 7; ++dj) {
          ushort4 wv = *(const ushort4*)(wp + (di * 7 + dj) * W_TAP_STR);
          float w0 = bf2f(wv.x), w1 = bf2f(wv.y), w2 = bf2f(wv.z),
                w3 = bf2f(wv.w);
          a00 += w0 * pf0[dj + 0];
          a01 += w1 * pf0[dj + 1];
          a02 += w2 * pf0[dj + 2];
          a03 += w3 * pf0[dj + 3];
          a10 += w0 * pf1[dj + 0];
          a11 += w1 * pf1[dj + 1];
          a12 += w2 * pf1[dj + 2];
          a13 += w3 * pf1[dj + 3];
        }
      }
      const int pxb = r0 * 56 + c0;
      {
        const float al = a2s[gc0], be = b2s[gc0];
        tb[(pxb + 0) * 16 + gc0] = bf16r(fast_tanh(al * a00 + be));
        tb[(pxb + 1) * 16 + gc0] = bf16r(fast_tanh(al * a01 + be));
        tb[(pxb + 2) * 16 + gc0] = bf16r(fast_tanh(al * a02 + be));
        tb[(pxb + 3) * 16 + gc0] = bf16r(fast_tanh(al * a03 + be));
      }
      {
        const float al = a2s[gc0 + 1], be = b2s[gc0 + 1];
        tb[(pxb + 0) * 16 + gc0 + 1] = bf16r(fast_tanh(al * a10 + be));
        tb[(pxb + 1) * 16 + gc0 + 1] = bf16r(fast_tanh(al * a11 + be));
        tb[(pxb + 2) * 16 + gc0 + 1] = bf16r(fast_tanh(al * a12 + be));
        tb[(pxb + 3) * 16 + gc0 + 1] = bf16r(fast_tanh(al * a13 + be));
      }
    }
  }
  __syncthreads();

  if (tid < 224) {
    unsigned short* dst = tT + ((size_t)b * HW_ + h0 * W_ + tid) * C_ + g * GC_;
    *(uint4*)(dst + 0) = *(const uint4*)&tb[tid * 16];
    *(uint4*)(dst + 8) = *(const uint4*)&tb[tid * 16 + 8];
  }
}

}  // namespace

extern "C" void kernel_launch(void* const* d_in, const int* in_sizes, int n_in,
                              void* d_out, int out_size, void* d_ws, size_t ws_size,
                              hipStream_t stream) {
  const float* x = (const float*)d_in[0];
  const float* w1 = (const float*)d_in[1];
  const float* b1 = (const float*)d_in[2];
  const float* bn1g = (const float*)d_in[3];
  const float* bn1b = (const float*)d_in[4];
  const float* bn1m = (const float*)d_in[5];
  const float* bn1v = (const float*)d_in[6];
  const float* red_w = (const float*)d_in[7];
  const float* red_b = (const float*)d_in[8];
  const float* rbg = (const float*)d_in[9];
  const float* rbb = (const float*)d_in[10];
  const float* rbm = (const float*)d_in[11];
  const float* rbv = (const float*)d_in[12];
  const float* span_w = (const float*)d_in[13];
  const float* span_b = (const float*)d_in[14];
  const float* bn2g = (const float*)d_in[15];
  const float* bn2b = (const float*)d_in[16];
  const float* bn2m = (const float*)d_in[17];
  const float* bn2v = (const float*)d_in[18];
  const float* w3 = (const float*)d_in[19];
  const float* b3 = (const float*)d_in[20];
  const float* bn3g = (const float*)d_in[21];
  const float* bn3b = (const float*)d_in[22];
  const float* bn3m = (const float*)d_in[23];
  const float* bn3v = (const float*)d_in[24];

  unsigned short* ws = (unsigned short*)d_ws;
  unsigned short* xT = ws;                       // (unused slot, kept layout)
  unsigned short* yT = xT + (size_t)NTOT * C_;   // 50176*256
  unsigned short* rT = yT + (size_t)NTOT * C_;   // 50176*64
  unsigned short* tT = rT + (size_t)NTOT * RED_; // 50176*256
  unsigned short* w1b = tT + (size_t)NTOT * C_;
  unsigned short* redb = w1b + 65536;
  unsigned short* spanb = redb + 16384;
  unsigned short* w3b = spanb + 50176;
  float* out = (float*)d_out;
  (void)xT;

  dim3 blk(256);
  wconv<<<dim3(256), blk, 0, stream>>>(w1, red_w, span_w, w3, w1b, redb, spanb, w3b);
  // y_T = tanh(bn1(w1 @ x)) AND r_T = relu(bn_red(red_w @ y)); x-transpose fused
  gemm_yr<<<dim3(784), blk, 0, stream>>>(
      w1b, x, redb, b1, bn1g, bn1b, bn1m, bn1v,
      red_b, rbg, rbb, rbm, rbv, yT, rT);
  // t_T = tanh(bn2(involution(y; span(r))))  — span fused in, g-fastest grid
  gather_inv<<<dim3(16, 14, 16), blk, 0, stream>>>(
      yT, rT, spanb, span_b, bn2g, bn2b, bn2m, bn2v, tT);
  // out = bn3(w3 @ t) + x  (planar fp32), LDS-free streaming GEMM
  gemm_out<<<dim3(392, 2), blk, 0, stream>>>(
      w3b, tT, b3, bn3g, bn3b, bn3m, bn3v, x, out);
}

// Round 7
// 261.108 us; speedup vs baseline: 1.1397x; 1.1397x over previous
//
#include <hip/hip_runtime.h>
#include <math.h>

#define DEV_EPS 1e-5f

namespace {
constexpr int B_ = 16, C_ = 256, H_ = 56, W_ = 56, HW_ = H_ * W_;
constexpr int G_ = 16, GC_ = 16, RED_ = 64, KK_ = 49;
constexpr int NTOT = B_ * HW_;  // 50176 flattened (batch, pixel)

typedef __attribute__((ext_vector_type(8))) short short8;
typedef __attribute__((ext_vector_type(4))) float f32x4;
typedef __attribute__((ext_vector_type(2))) float f32x2;

__device__ __forceinline__ unsigned short bf16r(float f) {
  unsigned u = __float_as_uint(f);
  u += 0x7fff + ((u >> 16) & 1);  // RNE
  return (unsigned short)(u >> 16);
}
__device__ __forceinline__ float bf2f(unsigned short s) {
  return __uint_as_float((unsigned)s << 16);
}

// tanh(x) = sign(x)*(1-e)/(1+e), e = exp(-2|x|).  ~8 VALU ops vs ~25 OCML.
__device__ __forceinline__ float fast_tanh(float x) {
  float ax = fabsf(x);
  float e = __expf(-2.0f * ax);
  float r = (1.0f - e) * __builtin_amdgcn_rcpf(1.0f + e);
  return copysignf(r, x);
}

// async global->LDS, 16B per lane (wave-uniform LDS base + lane*16, m104).
__device__ __forceinline__ void gl_lds16(const void* g, void* l) {
  __builtin_amdgcn_global_load_lds(
      (const __attribute__((address_space(1))) unsigned int*)g,
      (__attribute__((address_space(3))) unsigned int*)l, 16, 0, 0);
}

// ---------------------------------------------------------------------------
// gemm_yr (unchanged from v10):  y_T = tanh(bn1(w1 @ x));  r_T = relu(bnr(.))
// x-transpose fused (regs -> cvt -> swizzled ds_write), A-frags from global,
// T3-min 2-phase Bt dbuf.
// ---------------------------------------------------------------------------
constexpr int YS_STR = 264;  // ushort stride for yS [64 px][256 ch + 8 pad]

__global__ __launch_bounds__(256)
void gemm_yr(const unsigned short* __restrict__ A,     // w1b [256][256]
             const float* __restrict__ x,              // planar fp32
             const unsigned short* __restrict__ redw,  // redb [64][256]
             const float* __restrict__ p0,             // b1
             const float* __restrict__ bg, const float* __restrict__ bb,
             const float* __restrict__ bm, const float* __restrict__ bv,
             const float* __restrict__ rp0,            // red_b
             const float* __restrict__ rbg, const float* __restrict__ rbb,
             const float* __restrict__ rbm, const float* __restrict__ rbv,
             unsigned short* __restrict__ yT, unsigned short* __restrict__ rT) {
  __shared__ __align__(16) unsigned short blob2[16896];  // 33792 B
  __shared__ float aS[256], bS[256], aR[64], bR[64];
  unsigned short* Bt0 = blob2;         // [64][64]
  unsigned short* Bt1 = blob2 + 4096;  // [64][64]
  unsigned short* yS = blob2;          // [64][YS_STR] alias after loop

  const int tid = threadIdx.x;
  const int n0 = blockIdx.x * 64;           // 64-px tile; HW%64==0 -> same b
  const int bi = n0 / HW_, hw0 = n0 - bi * HW_;
  const int wave = tid >> 6, lane = tid & 63;
  const int quad = lane >> 4, ln = lane & 15;
  const int c2 = tid >> 3, pxo = tid & 7;   // ch-pair, px-octet for transpose

  {
    float sc = bg[tid] * rsqrtf(bv[tid] + DEV_EPS);
    aS[tid] = sc;
    bS[tid] = sc * p0[tid] + bb[tid] - bm[tid] * sc;
    if (tid < 64) {
      float s2 = rbg[tid] * rsqrtf(rbv[tid] + DEV_EPS);
      aR[tid] = s2;
      bR[tid] = s2 * rp0[tid] + rbb[tid] - rbm[tid] * s2;
    }
  }

  float4 xa, xb, xc, xd;  // 2 channels x 8 px fp32, in flight across compute
  auto load_x = [&](int kt) {
    const float* p = x + ((size_t)bi * C_ + kt * 64 + 2 * c2) * HW_ + hw0 + pxo * 8;
    xa = *(const float4*)p;
    xb = *(const float4*)(p + 4);
    xc = *(const float4*)(p + HW_);
    xd = *(const float4*)(p + HW_ + 4);
  };
  auto commit_x = [&](unsigned short* bt) {
    float e0[8] = {xa.x, xa.y, xa.z, xa.w, xb.x, xb.y, xb.z, xb.w};
    float e1[8] = {xc.x, xc.y, xc.z, xc.w, xd.x, xd.y, xd.z, xd.w};
    const int kc = c2 >> 2;          // k-chunk of this channel pair
    const int off = 2 * (c2 & 3);    // within-chunk ushort offset (even)
#pragma unroll
    for (int i = 0; i < 8; ++i) {
      int pxl = pxo * 8 + i;
      int slot = kc ^ (i & 7);       // pxl&7 == i (pxo*8 is 8-aligned)
      unsigned pk = (unsigned)bf16r(e0[i]) | ((unsigned)bf16r(e1[i]) << 16);
      *(unsigned*)&bt[pxl * 64 + slot * 8 + off] = pk;
    }
  };

  f32x4 acc[4][4];
#pragma unroll
  for (int i = 0; i < 4; ++i)
#pragma unroll
    for (int j = 0; j < 4; ++j)
#pragma unroll
      for (int e = 0; e < 4; ++e) acc[i][j][e] = 0.f;

  load_x(0);
  commit_x(Bt0);
  __syncthreads();

#pragma unroll 1
  for (int kt = 0; kt < 4; ++kt) {
    unsigned short* cur = (kt & 1) ? Bt1 : Bt0;
    unsigned short* nxt = (kt & 1) ? Bt0 : Bt1;
    if (kt < 3) load_x(kt + 1);  // in flight during compute (T3-min)
#pragma unroll
    for (int s = 0; s < 2; ++s) {
      const int c = s * 4 + quad;
      short8 af[4], bf[4];
#pragma unroll
      for (int i = 0; i < 4; ++i)
        af[i] = *(const short8*)&A[(size_t)(wave * 64 + i * 16 + ln) * 256 +
                                   kt * 64 + c * 8];
#pragma unroll
      for (int j = 0; j < 4; ++j) {
        int r = j * 16 + ln;
        bf[j] = *(const short8*)&cur[r * 64 + (c ^ (r & 7)) * 8];
      }
#pragma unroll
      for (int i = 0; i < 4; ++i)
#pragma unroll
        for (int j = 0; j < 4; ++j)
          acc[i][j] = __builtin_amdgcn_mfma_f32_16x16x32_bf16(af[i], bf[j],
                                                              acc[i][j], 0, 0, 0);
    }
    if (kt < 3) commit_x(nxt);  // cvt+ds_write after compute (latency hidden)
    __syncthreads();
  }

  // y epilogue: tanh(bn1) -> yT (global) + yS (LDS, [px][ch])
#pragma unroll
  for (int i = 0; i < 4; ++i) {
    const int mloc = wave * 64 + i * 16 + quad * 4;
#pragma unroll
    for (int j = 0; j < 4; ++j) {
      const int npl = j * 16 + ln;
      ushort4 pk;
      unsigned short* pp = (unsigned short*)&pk;
#pragma unroll
      for (int r = 0; r < 4; ++r) {
        float v = aS[mloc + r] * acc[i][j][r] + bS[mloc + r];
        pp[r] = bf16r(fast_tanh(v));
      }
      *(ushort4*)(yT + (size_t)(n0 + npl) * 256 + mloc) = pk;
      *(ushort4*)(yS + npl * YS_STR + mloc) = pk;
    }
  }
  __syncthreads();  // yS complete

  // RED GEMM: r[64][64px] = redw(64x256) @ yS^T ; A-frags from global (L2)
  f32x4 acc2[4];
#pragma unroll
  for (int j = 0; j < 4; ++j)
#pragma unroll
    for (int e = 0; e < 4; ++e) acc2[j][e] = 0.f;
#pragma unroll
  for (int kc = 0; kc < 8; ++kc) {
    short8 af2 =
        *(const short8*)&redw[(size_t)(wave * 16 + ln) * 256 + kc * 32 + quad * 8];
#pragma unroll
    for (int j = 0; j < 4; ++j) {
      short8 bf2 = *(const short8*)&yS[(j * 16 + ln) * YS_STR + kc * 32 + quad * 8];
      acc2[j] = __builtin_amdgcn_mfma_f32_16x16x32_bf16(af2, bf2, acc2[j], 0, 0, 0);
    }
  }
  {
    const int m2 = wave * 16 + quad * 4;
#pragma unroll
    for (int j = 0; j < 4; ++j) {
      const int np = n0 + j * 16 + ln;
      ushort4 pk;
      unsigned short* pp = (unsigned short*)&pk;
#pragma unroll
      for (int r = 0; r < 4; ++r) {
        float v = aR[m2 + r] * acc2[j][r] + bR[m2 + r];
        pp[r] = bf16r(fmaxf(v, 0.f));
      }
      *(ushort4*)(rT + (size_t)np * 64 + m2) = pk;
    }
  }
}

// ---------------------------------------------------------------------------
// gemm_out (REVERTED to v10 dbuf version — v11's LDS-free streaming variant
// regressed +26us: per-lane L2 operand loads at 4-wave occupancy couldn't
// hide latency, and tT L2 traffic was amplified 4x.  gl_lds staging + LDS
// reads win here.)
//  * A (w3b) frags from global/L2 (no At LDS).
//  * Bt (tT) double-buffered via gl_lds16; stage(kt+1) issued BEFORE
//    compute(kt) -> loads in flight under MFMA (T3-min); one barrier per kt.
//  LDS 32.5 KB -> 4 blocks/CU.
// ---------------------------------------------------------------------------
__global__ __launch_bounds__(256)
void gemm_out(const unsigned short* __restrict__ A,    // w3b [256][256]
              const unsigned short* __restrict__ Act,  // tT [NTOT][256]
              const float* __restrict__ p0,
              const float* __restrict__ bg, const float* __restrict__ bb,
              const float* __restrict__ bm, const float* __restrict__ bv,
              const float* __restrict__ xskip, float* __restrict__ out) {
  __shared__ __align__(16) unsigned short Bt[2][128 * 64];  // 32 KB
  __shared__ float aS[128], bS[128];

  const int tid = threadIdx.x;
  const int n0 = blockIdx.x * 128, m0 = blockIdx.y * 128;
  const int wave = tid >> 6, lane = tid & 63;
  const int wm = wave >> 1, wn = wave & 1;
  const int lq = lane & 7, lr8 = lane >> 3;
  const int quad = lane >> 4, ln = lane & 15;

  if (tid < 128) {
    int m = m0 + tid;
    float sc = bg[m] * rsqrtf(bv[m] + DEV_EPS);
    aS[tid] = sc;
    bS[tid] = sc * p0[m] + bb[m] - bm[m] * sc;
  }

  f32x4 acc[4][4];
#pragma unroll
  for (int i = 0; i < 4; ++i)
#pragma unroll
    for (int j = 0; j < 4; ++j)
#pragma unroll
      for (int e = 0; e < 4; ++e) acc[i][j][e] = 0.f;

  // prologue: stage Bt[0] for kt=0
#pragma unroll
  for (int t = 0; t < 4; ++t) {
    int inst = wave * 4 + t;
    int row = inst * 8 + lr8;
    int qs = lq ^ (row & 7);
    gl_lds16(Act + (size_t)(n0 + row) * 256 + qs * 8, &Bt[0][inst * 512]);
  }
  __syncthreads();

#pragma unroll 1
  for (int kt = 0; kt < 4; ++kt) {
    const int cur = kt & 1;
    if (kt < 3) {  // issue next-tile staging BEFORE compute
#pragma unroll
      for (int t = 0; t < 4; ++t) {
        int inst = wave * 4 + t;
        int row = inst * 8 + lr8;
        int qs = lq ^ (row & 7);
        gl_lds16(Act + (size_t)(n0 + row) * 256 + (kt + 1) * 64 + qs * 8,
                 &Bt[cur ^ 1][inst * 512]);
      }
    }
#pragma unroll
    for (int s = 0; s < 2; ++s) {
      const int c = s * 4 + quad;
      short8 af[4], bf[4];
#pragma unroll
      for (int i = 0; i < 4; ++i)
        af[i] = *(const short8*)&A[(size_t)(m0 + wm * 64 + i * 16 + ln) * 256 +
                                   kt * 64 + c * 8];
#pragma unroll
      for (int j = 0; j < 4; ++j) {
        int r = wn * 64 + j * 16 + ln;
        bf[j] = *(const short8*)&Bt[cur][r * 64 + (c ^ (r & 7)) * 8];
      }
#pragma unroll
      for (int i = 0; i < 4; ++i)
#pragma unroll
        for (int j = 0; j < 4; ++j)
          acc[i][j] = __builtin_amdgcn_mfma_f32_16x16x32_bf16(af[i], bf[j],
                                                              acc[i][j], 0, 0, 0);
    }
    __syncthreads();  // drains staged loads; next kt reads the other buffer
  }

  // epilogue: bn3 + x skip -> planar fp32
#pragma unroll
  for (int i = 0; i < 4; ++i) {
    const int mloc = wm * 64 + i * 16 + quad * 4;
#pragma unroll
    for (int j = 0; j < 4; ++j) {
      const int np = n0 + wn * 64 + j * 16 + ln;
      int b = np / HW_, hw = np - b * HW_;
      size_t base = ((size_t)b * C_ + m0 + mloc) * HW_ + hw;
#pragma unroll
      for (int r = 0; r < 4; ++r) {
        size_t o = base + (size_t)r * HW_;
        out[o] = aS[mloc + r] * acc[i][j][r] + bS[mloc + r] + xskip[o];
      }
    }
  }
}

// weights fp32 -> bf16 (all four mats)
__global__ __launch_bounds__(256)
void wconv(const float* __restrict__ w1, const float* __restrict__ rw,
           const float* __restrict__ sw, const float* __restrict__ w3,
           unsigned short* __restrict__ o1, unsigned short* __restrict__ orw,
           unsigned short* __restrict__ osw, unsigned short* __restrict__ ow3) {
  int i = blockIdx.x * 256 + threadIdx.x;
  if (i < 65536) o1[i] = bf16r(w1[i]);
  if (i < 16384) orw[i] = bf16r(rw[i]);
  if (i < 50176) osw[i] = bf16r(sw[i]);
  if (i < 65536) ow3[i] = bf16r(w3[i]);
}

// ---------------------------------------------------------------------------
// Gather v12: phase D packed over the gc axis with v_pk_fma_f32.
// Patch pair unpacked straight into f32x2 pfp[t] = {gc0[t], gc1[t]} (same
// unpack op count); dj loop = 4 cvt + 4 PACKED fma (was 4 cvt + 8 fma).
// Weight w_t enters as a scalar splat -> VOP3P op_sel broadcast, no extra
// movs.  ~25% VALU cut on the dominant phase.
// Kept: span GEMM fused; bf16 patch; aliased 51 KB blob (3 blocks/CU); T14
// patch prefetch; g-fastest grid; fast_tanh; gc-pair item mapping.
// ---------------------------------------------------------------------------
constexpr int PB_STR = 648;     // ushort patch plane stride (640 used + 8 pad)
constexpr int W_TAP_STR = 232;  // ushort: 224 px + 8 pad
constexpr int BLOB_N = 25320;   // 50640 B

__global__ __launch_bounds__(256)
void gather_inv(const unsigned short* __restrict__ yT,
                const unsigned short* __restrict__ rT,
                const unsigned short* __restrict__ spanw,  // [784][64] bf16
                const float* __restrict__ spanb,           // [784] fp32
                const float* __restrict__ g2, const float* __restrict__ b2,
                const float* __restrict__ m2, const float* __restrict__ v2,
                unsigned short* __restrict__ tT) {
  __shared__ __align__(16) unsigned short blob[BLOB_N];
  __shared__ float a2s[16], b2s[16], sbs[KK_];

  unsigned short* rs = blob;            // 224*64 shorts (swizzled rows)
  unsigned short* sws = blob + 14336;   // 64*64 shorts (swizzled rows)
  unsigned short* patchb = blob;        // [16][PB_STR] bf16 planes
  unsigned short* wts = blob + 10368;   // [49][W_TAP_STR]
  unsigned short* tb = blob + 21736;    // [224][16]

  const int tid = threadIdx.x;
  const int g = blockIdx.x;   // g fastest: 16 blocks sharing rT stripe adjacent
  const int st = blockIdx.y;  // 4-row stripe 0..13
  const int b = blockIdx.z;
  const int h0 = st * 4;
  const int wave = tid >> 6, lane = tid & 63;
  const int lq = lane & 7, lr8 = lane >> 3;
  const int quad = lane >> 4, ln = lane & 15;

  // ---- phase 0: issue patch global loads to regs ----
  uint4 pv0[3], pv1[3];
  int poff[3];
  bool pok[3];
#pragma unroll
  for (int pi = 0; pi < 3; ++pi) {
    int e = tid + pi * 256;
    bool ok = e < 620;
    int row = e / 62, cw = e - row * 62;
    int sr = h0 + row - 3, sc = cw - 3;
    poff[pi] = row * 64 + cw;
    pok[pi] = ok;
    bool inb = ok && sr >= 0 && sr < H_ && sc >= 0 && sc < W_;
    if (inb) {
      const unsigned short* yp =
          yT + ((size_t)b * HW_ + sr * W_ + sc) * C_ + g * GC_;
      pv0[pi] = *(const uint4*)yp;
      pv1[pi] = *(const uint4*)(yp + 8);
    } else {
      pv0[pi] = make_uint4(0, 0, 0, 0);
      pv1[pi] = make_uint4(0, 0, 0, 0);
    }
  }

  // ---- phase A: stage rs (224x64) + sws (64x64) via global_load_lds ----
  {
    const unsigned short* rbase = rT + ((size_t)b * HW_ + h0 * W_) * RED_;
#pragma unroll
    for (int t = 0; t < 7; ++t) {
      int inst = wave * 7 + t;
      int row = inst * 8 + lr8;
      int qs = lq ^ (row & 7);
      gl_lds16(rbase + (size_t)row * RED_ + qs * 8, &rs[inst * 512]);
    }
    const unsigned short* swg = spanw + (size_t)(g * KK_) * RED_;
#pragma unroll
    for (int t = 0; t < 2; ++t) {
      int inst = wave * 2 + t;
      int row = inst * 8 + lr8;
      int tap = min(row, KK_ - 1);
      int qs = lq ^ (row & 7);
      gl_lds16(swg + (size_t)tap * RED_ + qs * 8, &sws[inst * 512]);
    }
    if (tid < 16) {
      int c = g * GC_ + tid;
      float sc = g2[c] * rsqrtf(v2[c] + DEV_EPS);
      a2s[tid] = sc;
      b2s[tid] = b2[c] - m2[c] * sc;
    }
    if (tid < KK_) sbs[tid] = spanb[g * KK_ + tid];
  }
  __syncthreads();  // drains vmcnt: rs/sws in LDS, patch regs loaded

  // ---- phase B: mini-MFMA  (wave = tap-tile) ----
  f32x4 wacc[14];
#pragma unroll
  for (int j = 0; j < 14; ++j)
#pragma unroll
    for (int e = 0; e < 4; ++e) wacc[j][e] = 0.f;
  {
    short8 af[2];
#pragma unroll
    for (int s = 0; s < 2; ++s) {
      int c = s * 4 + quad;
      int r = wave * 16 + ln;
      af[s] = *(const short8*)&sws[r * 64 + (c ^ (r & 7)) * 8];
    }
#pragma unroll
    for (int j = 0; j < 14; ++j) {
#pragma unroll
      for (int s = 0; s < 2; ++s) {
        int c = s * 4 + quad;
        int r = j * 16 + ln;
        short8 bf = *(const short8*)&rs[r * 64 + (c ^ (r & 7)) * 8];
        wacc[j] = __builtin_amdgcn_mfma_f32_16x16x32_bf16(af[s], bf, wacc[j],
                                                          0, 0, 0);
      }
    }
  }
  __syncthreads();  // frag reads done; rs/sws dead -> blob reusable

  // ---- phase C: write wts[tap][px] bf16 + patch bf16 planes ----
  {
#pragma unroll
    for (int r = 0; r < 4; ++r) {
      int tap = wave * 16 + quad * 4 + r;
      if (tap < KK_) {
        float sb = sbs[tap];
#pragma unroll
        for (int j = 0; j < 14; ++j)
          wts[tap * W_TAP_STR + j * 16 + ln] = bf16r(wacc[j][r] + sb);
      }
    }
#pragma unroll
    for (int pi = 0; pi < 3; ++pi) {
      if (pok[pi]) {
        int off = poff[pi];
        unsigned wv[8] = {pv0[pi].x, pv0[pi].y, pv0[pi].z, pv0[pi].w,
                          pv1[pi].x, pv1[pi].y, pv1[pi].z, pv1[pi].w};
#pragma unroll
        for (int cc = 0; cc < 8; ++cc) {
          patchb[(2 * cc) * PB_STR + off] = (unsigned short)wv[cc];
          patchb[(2 * cc + 1) * PB_STR + off] = (unsigned short)(wv[cc] >> 16);
        }
      }
    }
  }
  __syncthreads();

  // ---- phase D: 7x7 gather; item = (gc-pair, px4 strip), pk_fma packed ----
#pragma unroll 1
  for (int it = 0; it < 2; ++it) {
    int item = tid + it * 256;
    if (item < 56 * 8) {
      const int gcp = item & 7, s = item >> 3;
      const int gc0 = gcp * 2;
      const int r0 = s / 14, c0 = (s - r0 * 14) * 4;
      const unsigned short* pg0 = patchb + gc0 * PB_STR + r0 * 64 + c0;
      const unsigned short* pg1 = pg0 + PB_STR;
      const unsigned short* wp = wts + (r0 * 56 + c0);
      f32x2 A0 = {0.f, 0.f}, A1 = {0.f, 0.f}, A2 = {0.f, 0.f}, A3 = {0.f, 0.f};
#pragma unroll
      for (int di = 0; di < 7; ++di) {
        const unsigned short* p0p = pg0 + di * 64;
        const unsigned short* p1p = pg1 + di * 64;
        uint2 q0 = *(const uint2*)p0p;
        uint2 q1 = *(const uint2*)(p0p + 4);
        uint2 q2 = *(const uint2*)(p0p + 8);
        uint2 u0 = *(const uint2*)p1p;
        uint2 u1 = *(const uint2*)(p1p + 4);
        uint2 u2 = *(const uint2*)(p1p + 8);
        unsigned uu0[6] = {q0.x, q0.y, q1.x, q1.y, q2.x, q2.y};
        unsigned uu1[6] = {u0.x, u0.y, u1.x, u1.y, u2.x, u2.y};
        f32x2 pfp[12];  // pfp[t] = {patch_gc0[t], patch_gc1[t]}
#pragma unroll
        for (int k = 0; k < 6; ++k) {
          pfp[2 * k][0] = __uint_as_float(uu0[k] << 16);
          pfp[2 * k][1] = __uint_as_float(uu1[k] << 16);
          pfp[2 * k + 1][0] = __uint_as_float(uu0[k] & 0xffff0000u);
          pfp[2 * k + 1][1] = __uint_as_float(uu1[k] & 0xffff0000u);
        }
#pragma unroll
        for (int dj = 0; dj < 7; ++dj) {
          ushort4 wv = *(const ushort4*)(wp + (di * 7 + dj) * W_TAP_STR);
          A0 += pfp[dj + 0] * bf2f(wv.x);  // v_pk_fma_f32, w splat via op_sel
          A1 += pfp[dj + 1] * bf2f(wv.y);
          A2 += pfp[dj + 2] * bf2f(wv.z);
          A3 += pfp[dj + 3] * bf2f(wv.w);
        }
      }
      const int pxb = r0 * 56 + c0;
      const float al0 = a2s[gc0], be0 = b2s[gc0];
      const float al1 = a2s[gc0 + 1], be1 = b2s[gc0 + 1];
      tb[(pxb + 0) * 16 + gc0] = bf16r(fast_tanh(al0 * A0[0] + be0));
      tb[(pxb + 1) * 16 + gc0] = bf16r(fast_tanh(al0 * A1[0] + be0));
      tb[(pxb + 2) * 16 + gc0] = bf16r(fast_tanh(al0 * A2[0] + be0));
      tb[(pxb + 3) * 16 + gc0] = bf16r(fast_tanh(al0 * A3[0] + be0));
      tb[(pxb + 0) * 16 + gc0 + 1] = bf16r(fast_tanh(al1 * A0[1] + be1));
      tb[(pxb + 1) * 16 + gc0 + 1] = bf16r(fast_tanh(al1 * A1[1] + be1));
      tb[(pxb + 2) * 16 + gc0 + 1] = bf16r(fast_tanh(al1 * A2[1] + be1));
      tb[(pxb + 3) * 16 + gc0 + 1] = bf16r(fast_tanh(al1 * A3[1] + be1));
    }
  }
  __syncthreads();

  if (tid < 224) {
    unsigned short* dst = tT + ((size_t)b * HW_ + h0 * W_ + tid) * C_ + g * GC_;
    *(uint4*)(dst + 0) = *(const uint4*)&tb[tid * 16];
    *(uint4*)(dst + 8) = *(const uint4*)&tb[tid * 16 + 8];
  }
}

}  // namespace

extern "C" void kernel_launch(void* const* d_in, const int* in_sizes, int n_in,
                              void* d_out, int out_size, void* d_ws, size_t ws_size,
                              hipStream_t stream) {
  const float* x = (const float*)d_in[0];
  const float* w1 = (const float*)d_in[1];
  const float* b1 = (const float*)d_in[2];
  const float* bn1g = (const float*)d_in[3];
  const float* bn1b = (const float*)d_in[4];
  const float* bn1m = (const float*)d_in[5];
  const float* bn1v = (const float*)d_in[6];
  const float* red_w = (const float*)d_in[7];
  const float* red_b = (const float*)d_in[8];
  const float* rbg = (const float*)d_in[9];
  const float* rbb = (const float*)d_in[10];
  const float* rbm = (const float*)d_in[11];
  const float* rbv = (const float*)d_in[12];
  const float* span_w = (const float*)d_in[13];
  const float* span_b = (const float*)d_in[14];
  const float* bn2g = (const float*)d_in[15];
  const float* bn2b = (const float*)d_in[16];
  const float* bn2m = (const float*)d_in[17];
  const float* bn2v = (const float*)d_in[18];
  const float* w3 = (const float*)d_in[19];
  const float* b3 = (const float*)d_in[20];
  const float* bn3g = (const float*)d_in[21];
  const float* bn3b = (const float*)d_in[22];
  const float* bn3m = (const float*)d_in[23];
  const float* bn3v = (const float*)d_in[24];

  unsigned short* ws = (unsigned short*)d_ws;
  unsigned short* xT = ws;                       // (unused slot, kept layout)
  unsigned short* yT = xT + (size_t)NTOT * C_;   // 50176*256
  unsigned short* rT = yT + (size_t)NTOT * C_;   // 50176*64
  unsigned short* tT = rT + (size_t)NTOT * RED_; // 50176*256
  unsigned short* w1b = tT + (size_t)NTOT * C_;
  unsigned short* redb = w1b + 65536;
  unsigned short* spanb = redb + 16384;
  unsigned short* w3b = spanb + 50176;
  float* out = (float*)d_out;
  (void)xT;

  dim3 blk(256);
  wconv<<<dim3(256), blk, 0, stream>>>(w1, red_w, span_w, w3, w1b, redb, spanb, w3b);
  // y_T = tanh(bn1(w1 @ x)) AND r_T = relu(bn_red(red_w @ y)); x-transpose fused
  gemm_yr<<<dim3(784), blk, 0, stream>>>(
      w1b, x, redb, b1, bn1g, bn1b, bn1m, bn1v,
      red_b, rbg, rbb, rbm, rbv, yT, rT);
  // t_T = tanh(bn2(involution(y; span(r))))  — span fused in, g-fastest grid
  gather_inv<<<dim3(16, 14, 16), blk, 0, stream>>>(
      yT, rT, spanb, span_b, bn2g, bn2b, bn2m, bn2v, tT);
  // out = bn3(w3 @ t) + x  (planar fp32), dbuf-pipelined (v10 version)
  gemm_out<<<dim3(392, 2), blk, 0, stream>>>(
      w3b, tT, b3, bn3g, bn3b, bn3m, bn3v, x, out);
}

// Round 9
// 254.330 us; speedup vs baseline: 1.1701x; 1.0267x over previous
//
#include <hip/hip_runtime.h>
#include <math.h>

#define DEV_EPS 1e-5f

namespace {
constexpr int B_ = 16, C_ = 256, H_ = 56, W_ = 56, HW_ = H_ * W_;
constexpr int G_ = 16, GC_ = 16, RED_ = 64, KK_ = 49;
constexpr int NTOT = B_ * HW_;  // 50176 flattened (batch, pixel)

typedef __attribute__((ext_vector_type(8))) short short8;
typedef __attribute__((ext_vector_type(4))) float f32x4;
typedef __attribute__((ext_vector_type(2))) float f32x2;

__device__ __forceinline__ unsigned short bf16r(float f) {
  unsigned u = __float_as_uint(f);
  u += 0x7fff + ((u >> 16) & 1);  // RNE
  return (unsigned short)(u >> 16);
}
__device__ __forceinline__ float bf2f(unsigned short s) {
  return __uint_as_float((unsigned)s << 16);
}

// tanh(x) = sign(x)*(1-e)/(1+e), e = exp(-2|x|).  ~8 VALU ops vs ~25 OCML.
__device__ __forceinline__ float fast_tanh(float x) {
  float ax = fabsf(x);
  float e = __expf(-2.0f * ax);
  float r = (1.0f - e) * __builtin_amdgcn_rcpf(1.0f + e);
  return copysignf(r, x);
}

// async global->LDS, 16B per lane (wave-uniform LDS base + lane*16, m104).
__device__ __forceinline__ void gl_lds16(const void* g, void* l) {
  __builtin_amdgcn_global_load_lds(
      (const __attribute__((address_space(1))) unsigned int*)g,
      (__attribute__((address_space(3))) unsigned int*)l, 16, 0, 0);
}

// ---------------------------------------------------------------------------
// gemm_yr (unchanged from v10):  y_T = tanh(bn1(w1 @ x));  r_T = relu(bnr(.))
// x-transpose fused (regs -> cvt -> swizzled ds_write), A-frags from global,
// T3-min 2-phase Bt dbuf.
// ---------------------------------------------------------------------------
constexpr int YS_STR = 264;  // ushort stride for yS [64 px][256 ch + 8 pad]

__global__ __launch_bounds__(256)
void gemm_yr(const unsigned short* __restrict__ A,     // w1b [256][256]
             const float* __restrict__ x,              // planar fp32
             const unsigned short* __restrict__ redw,  // redb [64][256]
             const float* __restrict__ p0,             // b1
             const float* __restrict__ bg, const float* __restrict__ bb,
             const float* __restrict__ bm, const float* __restrict__ bv,
             const float* __restrict__ rp0,            // red_b
             const float* __restrict__ rbg, const float* __restrict__ rbb,
             const float* __restrict__ rbm, const float* __restrict__ rbv,
             unsigned short* __restrict__ yT, unsigned short* __restrict__ rT) {
  __shared__ __align__(16) unsigned short blob2[16896];  // 33792 B
  __shared__ float aS[256], bS[256], aR[64], bR[64];
  unsigned short* Bt0 = blob2;         // [64][64]
  unsigned short* Bt1 = blob2 + 4096;  // [64][64]
  unsigned short* yS = blob2;          // [64][YS_STR] alias after loop

  const int tid = threadIdx.x;
  const int n0 = blockIdx.x * 64;           // 64-px tile; HW%64==0 -> same b
  const int bi = n0 / HW_, hw0 = n0 - bi * HW_;
  const int wave = tid >> 6, lane = tid & 63;
  const int quad = lane >> 4, ln = lane & 15;
  const int c2 = tid >> 3, pxo = tid & 7;   // ch-pair, px-octet for transpose

  {
    float sc = bg[tid] * rsqrtf(bv[tid] + DEV_EPS);
    aS[tid] = sc;
    bS[tid] = sc * p0[tid] + bb[tid] - bm[tid] * sc;
    if (tid < 64) {
      float s2 = rbg[tid] * rsqrtf(rbv[tid] + DEV_EPS);
      aR[tid] = s2;
      bR[tid] = s2 * rp0[tid] + rbb[tid] - rbm[tid] * s2;
    }
  }

  float4 xa, xb, xc, xd;  // 2 channels x 8 px fp32, in flight across compute
  auto load_x = [&](int kt) {
    const float* p = x + ((size_t)bi * C_ + kt * 64 + 2 * c2) * HW_ + hw0 + pxo * 8;
    xa = *(const float4*)p;
    xb = *(const float4*)(p + 4);
    xc = *(const float4*)(p + HW_);
    xd = *(const float4*)(p + HW_ + 4);
  };
  auto commit_x = [&](unsigned short* bt) {
    float e0[8] = {xa.x, xa.y, xa.z, xa.w, xb.x, xb.y, xb.z, xb.w};
    float e1[8] = {xc.x, xc.y, xc.z, xc.w, xd.x, xd.y, xd.z, xd.w};
    const int kc = c2 >> 2;          // k-chunk of this channel pair
    const int off = 2 * (c2 & 3);    // within-chunk ushort offset (even)
#pragma unroll
    for (int i = 0; i < 8; ++i) {
      int pxl = pxo * 8 + i;
      int slot = kc ^ (i & 7);       // pxl&7 == i (pxo*8 is 8-aligned)
      unsigned pk = (unsigned)bf16r(e0[i]) | ((unsigned)bf16r(e1[i]) << 16);
      *(unsigned*)&bt[pxl * 64 + slot * 8 + off] = pk;
    }
  };

  f32x4 acc[4][4];
#pragma unroll
  for (int i = 0; i < 4; ++i)
#pragma unroll
    for (int j = 0; j < 4; ++j)
#pragma unroll
      for (int e = 0; e < 4; ++e) acc[i][j][e] = 0.f;

  load_x(0);
  commit_x(Bt0);
  __syncthreads();

#pragma unroll 1
  for (int kt = 0; kt < 4; ++kt) {
    unsigned short* cur = (kt & 1) ? Bt1 : Bt0;
    unsigned short* nxt = (kt & 1) ? Bt0 : Bt1;
    if (kt < 3) load_x(kt + 1);  // in flight during compute (T3-min)
#pragma unroll
    for (int s = 0; s < 2; ++s) {
      const int c = s * 4 + quad;
      short8 af[4], bf[4];
#pragma unroll
      for (int i = 0; i < 4; ++i)
        af[i] = *(const short8*)&A[(size_t)(wave * 64 + i * 16 + ln) * 256 +
                                   kt * 64 + c * 8];
#pragma unroll
      for (int j = 0; j < 4; ++j) {
        int r = j * 16 + ln;
        bf[j] = *(const short8*)&cur[r * 64 + (c ^ (r & 7)) * 8];
      }
#pragma unroll
      for (int i = 0; i < 4; ++i)
#pragma unroll
        for (int j = 0; j < 4; ++j)
          acc[i][j] = __builtin_amdgcn_mfma_f32_16x16x32_bf16(af[i], bf[j],
                                                              acc[i][j], 0, 0, 0);
    }
    if (kt < 3) commit_x(nxt);  // cvt+ds_write after compute (latency hidden)
    __syncthreads();
  }

  // y epilogue: tanh(bn1) -> yT (global) + yS (LDS, [px][ch])
#pragma unroll
  for (int i = 0; i < 4; ++i) {
    const int mloc = wave * 64 + i * 16 + quad * 4;
#pragma unroll
    for (int j = 0; j < 4; ++j) {
      const int npl = j * 16 + ln;
      ushort4 pk;
      unsigned short* pp = (unsigned short*)&pk;
#pragma unroll
      for (int r = 0; r < 4; ++r) {
        float v = aS[mloc + r] * acc[i][j][r] + bS[mloc + r];
        pp[r] = bf16r(fast_tanh(v));
      }
      *(ushort4*)(yT + (size_t)(n0 + npl) * 256 + mloc) = pk;
      *(ushort4*)(yS + npl * YS_STR + mloc) = pk;
    }
  }
  __syncthreads();  // yS complete

  // RED GEMM: r[64][64px] = redw(64x256) @ yS^T ; A-frags from global (L2)
  f32x4 acc2[4];
#pragma unroll
  for (int j = 0; j < 4; ++j)
#pragma unroll
    for (int e = 0; e < 4; ++e) acc2[j][e] = 0.f;
#pragma unroll
  for (int kc = 0; kc < 8; ++kc) {
    short8 af2 =
        *(const short8*)&redw[(size_t)(wave * 16 + ln) * 256 + kc * 32 + quad * 8];
#pragma unroll
    for (int j = 0; j < 4; ++j) {
      short8 bf2 = *(const short8*)&yS[(j * 16 + ln) * YS_STR + kc * 32 + quad * 8];
      acc2[j] = __builtin_amdgcn_mfma_f32_16x16x32_bf16(af2, bf2, acc2[j], 0, 0, 0);
    }
  }
  {
    const int m2 = wave * 16 + quad * 4;
#pragma unroll
    for (int j = 0; j < 4; ++j) {
      const int np = n0 + j * 16 + ln;
      ushort4 pk;
      unsigned short* pp = (unsigned short*)&pk;
#pragma unroll
      for (int r = 0; r < 4; ++r) {
        float v = aR[m2 + r] * acc2[j][r] + bR[m2 + r];
        pp[r] = bf16r(fmaxf(v, 0.f));
      }
      *(ushort4*)(rT + (size_t)np * 64 + m2) = pk;
    }
  }
}

// ---------------------------------------------------------------------------
// gemm_out (v10 dbuf version — known-good):
//  * A (w3b) frags from global/L2 (no At LDS).
//  * Bt (tT) double-buffered via gl_lds16; stage(kt+1) issued BEFORE
//    compute(kt); one barrier per kt.  LDS 32.5 KB -> 4 blocks/CU.
// ---------------------------------------------------------------------------
__global__ __launch_bounds__(256)
void gemm_out(const unsigned short* __restrict__ A,    // w3b [256][256]
              const unsigned short* __restrict__ Act,  // tT [NTOT][256]
              const float* __restrict__ p0,
              const float* __restrict__ bg, const float* __restrict__ bb,
              const float* __restrict__ bm, const float* __restrict__ bv,
              const float* __restrict__ xskip, float* __restrict__ out) {
  __shared__ __align__(16) unsigned short Bt[2][128 * 64];  // 32 KB
  __shared__ float aS[128], bS[128];

  const int tid = threadIdx.x;
  const int n0 = blockIdx.x * 128, m0 = blockIdx.y * 128;
  const int wave = tid >> 6, lane = tid & 63;
  const int wm = wave >> 1, wn = wave & 1;
  const int lq = lane & 7, lr8 = lane >> 3;
  const int quad = lane >> 4, ln = lane & 15;

  if (tid < 128) {
    int m = m0 + tid;
    float sc = bg[m] * rsqrtf(bv[m] + DEV_EPS);
    aS[tid] = sc;
    bS[tid] = sc * p0[m] + bb[m] - bm[m] * sc;
  }

  f32x4 acc[4][4];
#pragma unroll
  for (int i = 0; i < 4; ++i)
#pragma unroll
    for (int j = 0; j < 4; ++j)
#pragma unroll
      for (int e = 0; e < 4; ++e) acc[i][j][e] = 0.f;

  // prologue: stage Bt[0] for kt=0
#pragma unroll
  for (int t = 0; t < 4; ++t) {
    int inst = wave * 4 + t;
    int row = inst * 8 + lr8;
    int qs = lq ^ (row & 7);
    gl_lds16(Act + (size_t)(n0 + row) * 256 + qs * 8, &Bt[0][inst * 512]);
  }
  __syncthreads();

#pragma unroll 1
  for (int kt = 0; kt < 4; ++kt) {
    const int cur = kt & 1;
    if (kt < 3) {  // issue next-tile staging BEFORE compute
#pragma unroll
      for (int t = 0; t < 4; ++t) {
        int inst = wave * 4 + t;
        int row = inst * 8 + lr8;
        int qs = lq ^ (row & 7);
        gl_lds16(Act + (size_t)(n0 + row) * 256 + (kt + 1) * 64 + qs * 8,
                 &Bt[cur ^ 1][inst * 512]);
      }
    }
#pragma unroll
    for (int s = 0; s < 2; ++s) {
      const int c = s * 4 + quad;
      short8 af[4], bf[4];
#pragma unroll
      for (int i = 0; i < 4; ++i)
        af[i] = *(const short8*)&A[(size_t)(m0 + wm * 64 + i * 16 + ln) * 256 +
                                   kt * 64 + c * 8];
#pragma unroll
      for (int j = 0; j < 4; ++j) {
        int r = wn * 64 + j * 16 + ln;
        bf[j] = *(const short8*)&Bt[cur][r * 64 + (c ^ (r & 7)) * 8];
      }
#pragma unroll
      for (int i = 0; i < 4; ++i)
#pragma unroll
        for (int j = 0; j < 4; ++j)
          acc[i][j] = __builtin_amdgcn_mfma_f32_16x16x32_bf16(af[i], bf[j],
                                                              acc[i][j], 0, 0, 0);
    }
    __syncthreads();  // drains staged loads; next kt reads the other buffer
  }

  // epilogue: bn3 + x skip -> planar fp32
#pragma unroll
  for (int i = 0; i < 4; ++i) {
    const int mloc = wm * 64 + i * 16 + quad * 4;
#pragma unroll
    for (int j = 0; j < 4; ++j) {
      const int np = n0 + wn * 64 + j * 16 + ln;
      int b = np / HW_, hw = np - b * HW_;
      size_t base = ((size_t)b * C_ + m0 + mloc) * HW_ + hw;
#pragma unroll
      for (int r = 0; r < 4; ++r) {
        size_t o = base + (size_t)r * HW_;
        out[o] = aS[mloc + r] * acc[i][j][r] + bS[mloc + r] + xskip[o];
      }
    }
  }
}

// weights fp32 -> bf16 (all four mats)
__global__ __launch_bounds__(256)
void wconv(const float* __restrict__ w1, const float* __restrict__ rw,
           const float* __restrict__ sw, const float* __restrict__ w3,
           unsigned short* __restrict__ o1, unsigned short* __restrict__ orw,
           unsigned short* __restrict__ osw, unsigned short* __restrict__ ow3) {
  int i = blockIdx.x * 256 + threadIdx.x;
  if (i < 65536) o1[i] = bf16r(w1[i]);
  if (i < 16384) orw[i] = bf16r(rw[i]);
  if (i < 50176) osw[i] = bf16r(sw[i]);
  if (i < 65536) ow3[i] = bf16r(w3[i]);
}

// ---------------------------------------------------------------------------
// Gather v13: 512-thread blocks (8 waves).  Same LDS blob (51.2 KB) still
// fits 3 blocks/CU => wave ceiling 12 -> 24 waves/CU (37.5% -> 75%).
// Phase B/C: wave = (tap-group tg, j-half jh); each wave computes 7 of 14
// j-tiles for its 16 taps (wacc[14] -> wacc[7]).  Phase 0: 2 prefetch slots.
// Phase D: single 448-item pass.  All layouts/algorithms unchanged.
// (Round-8 resubmit: previous bench was a container-infra failure; kernel
// audited — uniform barriers, guarded staging, in-bounds LDS regions.)
// ---------------------------------------------------------------------------
constexpr int PB_STR = 648;     // ushort patch plane stride (640 used + 8 pad)
constexpr int W_TAP_STR = 232;  // ushort: 224 px + 8 pad
constexpr int BLOB_N = 25320;   // 50640 B

__global__ __launch_bounds__(512)
void gather_inv(const unsigned short* __restrict__ yT,
                const unsigned short* __restrict__ rT,
                const unsigned short* __restrict__ spanw,  // [784][64] bf16
                const float* __restrict__ spanb,           // [784] fp32
                const float* __restrict__ g2, const float* __restrict__ b2,
                const float* __restrict__ m2, const float* __restrict__ v2,
                unsigned short* __restrict__ tT) {
  __shared__ __align__(16) unsigned short blob[BLOB_N];
  __shared__ float a2s[16], b2s[16], sbs[KK_];

  unsigned short* rs = blob;            // 224*64 shorts (swizzled rows)
  unsigned short* sws = blob + 14336;   // 64*64 shorts (swizzled rows)
  unsigned short* patchb = blob;        // [16][PB_STR] bf16 planes
  unsigned short* wts = blob + 10368;   // [49][W_TAP_STR]
  unsigned short* tb = blob + 21736;    // [224][16]

  const int tid = threadIdx.x;          // 0..511
  const int g = blockIdx.x;   // g fastest: 16 blocks sharing rT stripe adjacent
  const int st = blockIdx.y;  // 4-row stripe 0..13
  const int b = blockIdx.z;
  const int h0 = st * 4;
  const int wave = tid >> 6, lane = tid & 63;
  const int lq = lane & 7, lr8 = lane >> 3;
  const int quad = lane >> 4, ln = lane & 15;

  // ---- phase 0: issue patch global loads to regs (2 slots x 512 thr) ----
  uint4 pv0[2], pv1[2];
  int poff[2];
  bool pok[2];
#pragma unroll
  for (int pi = 0; pi < 2; ++pi) {
    int e = tid + pi * 512;
    bool ok = e < 620;
    int row = ok ? (e / 62) : 0;
    int cw = ok ? (e - row * 62) : 0;
    int sr = h0 + row - 3, sc = cw - 3;
    poff[pi] = row * 64 + cw;
    pok[pi] = ok;
    bool inb = ok && sr >= 0 && sr < H_ && sc >= 0 && sc < W_;
    if (inb) {
      const unsigned short* yp =
          yT + ((size_t)b * HW_ + sr * W_ + sc) * C_ + g * GC_;
      pv0[pi] = *(const uint4*)yp;
      pv1[pi] = *(const uint4*)(yp + 8);
    } else {
      pv0[pi] = make_uint4(0, 0, 0, 0);
      pv1[pi] = make_uint4(0, 0, 0, 0);
    }
  }

  // ---- phase A: stage rs (224x64, 28 insts) + sws (64x64, 8 insts) ----
  {
    const unsigned short* rbase = rT + ((size_t)b * HW_ + h0 * W_) * RED_;
#pragma unroll
    for (int t = 0; t < 4; ++t) {
      int inst = wave * 4 + t;
      if (inst < 28) {
        int row = inst * 8 + lr8;
        int qs = lq ^ (row & 7);
        gl_lds16(rbase + (size_t)row * RED_ + qs * 8, &rs[inst * 512]);
      }
    }
    {
      int inst = wave;  // 8 insts, one per wave
      int row = inst * 8 + lr8;
      int tap = min(row, KK_ - 1);
      int qs = lq ^ (row & 7);
      gl_lds16(spanw + (size_t)(g * KK_ + tap) * RED_ + qs * 8,
               &sws[inst * 512]);
    }
    if (tid < 16) {
      int c = g * GC_ + tid;
      float sc = g2[c] * rsqrtf(v2[c] + DEV_EPS);
      a2s[tid] = sc;
      b2s[tid] = b2[c] - m2[c] * sc;
    }
    if (tid < KK_) sbs[tid] = spanb[g * KK_ + tid];
  }
  __syncthreads();  // drains vmcnt: rs/sws in LDS, patch regs loaded

  // ---- phase B: mini-MFMA;  wave = (tap-group tg, j-half jh) ----
  const int tg = wave >> 1, jh = wave & 1;
  f32x4 wacc[7];
#pragma unroll
  for (int jj = 0; jj < 7; ++jj)
#pragma unroll
    for (int e = 0; e < 4; ++e) wacc[jj][e] = 0.f;
  {
    short8 af[2];
#pragma unroll
    for (int s = 0; s < 2; ++s) {
      int c = s * 4 + quad;
      int r = tg * 16 + ln;
      af[s] = *(const short8*)&sws[r * 64 + (c ^ (r & 7)) * 8];
    }
#pragma unroll
    for (int jj = 0; jj < 7; ++jj) {
      int j = jh * 7 + jj;
#pragma unroll
      for (int s = 0; s < 2; ++s) {
        int c = s * 4 + quad;
        int r = j * 16 + ln;
        short8 bf = *(const short8*)&rs[r * 64 + (c ^ (r & 7)) * 8];
        wacc[jj] = __builtin_amdgcn_mfma_f32_16x16x32_bf16(af[s], bf, wacc[jj],
                                                           0, 0, 0);
      }
    }
  }
  __syncthreads();  // frag reads done; rs/sws dead -> blob reusable

  // ---- phase C: write wts[tap][px] bf16 + patch bf16 planes ----
  {
#pragma unroll
    for (int r = 0; r < 4; ++r) {
      int tap = tg * 16 + quad * 4 + r;
      if (tap < KK_) {
        float sb = sbs[tap];
#pragma unroll
        for (int jj = 0; jj < 7; ++jj) {
          int j = jh * 7 + jj;
          wts[tap * W_TAP_STR + j * 16 + ln] = bf16r(wacc[jj][r] + sb);
        }
      }
    }
#pragma unroll
    for (int pi = 0; pi < 2; ++pi) {
      if (pok[pi]) {
        int off = poff[pi];
        unsigned wv[8] = {pv0[pi].x, pv0[pi].y, pv0[pi].z, pv0[pi].w,
                          pv1[pi].x, pv1[pi].y, pv1[pi].z, pv1[pi].w};
#pragma unroll
        for (int cc = 0; cc < 8; ++cc) {
          patchb[(2 * cc) * PB_STR + off] = (unsigned short)wv[cc];
          patchb[(2 * cc + 1) * PB_STR + off] = (unsigned short)(wv[cc] >> 16);
        }
      }
    }
  }
  __syncthreads();

  // ---- phase D: 7x7 gather; item = (gc-pair, px4 strip), pk_fma packed ----
  {
    int item = tid;  // 448 items on 512 threads, single pass
    if (item < 56 * 8) {
      const int gcp = item & 7, s = item >> 3;
      const int gc0 = gcp * 2;
      const int r0 = s / 14, c0 = (s - r0 * 14) * 4;
      const unsigned short* pg0 = patchb + gc0 * PB_STR + r0 * 64 + c0;
      const unsigned short* pg1 = pg0 + PB_STR;
      const unsigned short* wp = wts + (r0 * 56 + c0);
      f32x2 A0 = {0.f, 0.f}, A1 = {0.f, 0.f}, A2 = {0.f, 0.f}, A3 = {0.f, 0.f};
#pragma unroll
      for (int di = 0; di < 7; ++di) {
        const unsigned short* p0p = pg0 + di * 64;
        const unsigned short* p1p = pg1 + di * 64;
        uint2 q0 = *(const uint2*)p0p;
        uint2 q1 = *(const uint2*)(p0p + 4);
        uint2 q2 = *(const uint2*)(p0p + 8);
        uint2 u0 = *(const uint2*)p1p;
        uint2 u1 = *(const uint2*)(p1p + 4);
        uint2 u2 = *(const uint2*)(p1p + 8);
        unsigned uu0[6] = {q0.x, q0.y, q1.x, q1.y, q2.x, q2.y};
        unsigned uu1[6] = {u0.x, u0.y, u1.x, u1.y, u2.x, u2.y};
        f32x2 pfp[12];  // pfp[t] = {patch_gc0[t], patch_gc1[t]}
#pragma unroll
        for (int k = 0; k < 6; ++k) {
          pfp[2 * k][0] = __uint_as_float(uu0[k] << 16);
          pfp[2 * k][1] = __uint_as_float(uu1[k] << 16);
          pfp[2 * k + 1][0] = __uint_as_float(uu0[k] & 0xffff0000u);
          pfp[2 * k + 1][1] = __uint_as_float(uu1[k] & 0xffff0000u);
        }
#pragma unroll
        for (int dj = 0; dj < 7; ++dj) {
          ushort4 wv = *(const ushort4*)(wp + (di * 7 + dj) * W_TAP_STR);
          A0 += pfp[dj + 0] * bf2f(wv.x);  // v_pk_fma_f32, w splat via op_sel
          A1 += pfp[dj + 1] * bf2f(wv.y);
          A2 += pfp[dj + 2] * bf2f(wv.z);
          A3 += pfp[dj + 3] * bf2f(wv.w);
        }
      }
      const int pxb = r0 * 56 + c0;
      const float al0 = a2s[gc0], be0 = b2s[gc0];
      const float al1 = a2s[gc0 + 1], be1 = b2s[gc0 + 1];
      tb[(pxb + 0) * 16 + gc0] = bf16r(fast_tanh(al0 * A0[0] + be0));
      tb[(pxb + 1) * 16 + gc0] = bf16r(fast_tanh(al0 * A1[0] + be0));
      tb[(pxb + 2) * 16 + gc0] = bf16r(fast_tanh(al0 * A2[0] + be0));
      tb[(pxb + 3) * 16 + gc0] = bf16r(fast_tanh(al0 * A3[0] + be0));
      tb[(pxb + 0) * 16 + gc0 + 1] = bf16r(fast_tanh(al1 * A0[1] + be1));
      tb[(pxb + 1) * 16 + gc0 + 1] = bf16r(fast_tanh(al1 * A1[1] + be1));
      tb[(pxb + 2) * 16 + gc0 + 1] = bf16r(fast_tanh(al1 * A2[1] + be1));
      tb[(pxb + 3) * 16 + gc0 + 1] = bf16r(fast_tanh(al1 * A3[1] + be1));
    }
  }
  __syncthreads();

  if (tid < 224) {
    unsigned short* dst = tT + ((size_t)b * HW_ + h0 * W_ + tid) * C_ + g * GC_;
    *(uint4*)(dst + 0) = *(const uint4*)&tb[tid * 16];
    *(uint4*)(dst + 8) = *(const uint4*)&tb[tid * 16 + 8];
  }
}

}  // namespace

extern "C" void kernel_launch(void* const* d_in, const int* in_sizes, int n_in,
                              void* d_out, int out_size, void* d_ws, size_t ws_size,
                              hipStream_t stream) {
  const float* x = (const float*)d_in[0];
  const float* w1 = (const float*)d_in[1];
  const float* b1 = (const float*)d_in[2];
  const float* bn1g = (const float*)d_in[3];
  const float* bn1b = (const float*)d_in[4];
  const float* bn1m = (const float*)d_in[5];
  const float* bn1v = (const float*)d_in[6];
  const float* red_w = (const float*)d_in[7];
  const float* red_b = (const float*)d_in[8];
  const float* rbg = (const float*)d_in[9];
  const float* rbb = (const float*)d_in[10];
  const float* rbm = (const float*)d_in[11];
  const float* rbv = (const float*)d_in[12];
  const float* span_w = (const float*)d_in[13];
  const float* span_b = (const float*)d_in[14];
  const float* bn2g = (const float*)d_in[15];
  const float* bn2b = (const float*)d_in[16];
  const float* bn2m = (const float*)d_in[17];
  const float* bn2v = (const float*)d_in[18];
  const float* w3 = (const float*)d_in[19];
  const float* b3 = (const float*)d_in[20];
  const float* bn3g = (const float*)d_in[21];
  const float* bn3b = (const float*)d_in[22];
  const float* bn3m = (const float*)d_in[23];
  const float* bn3v = (const float*)d_in[24];

  unsigned short* ws = (unsigned short*)d_ws;
  unsigned short* xT = ws;                       // (unused slot, kept layout)
  unsigned short* yT = xT + (size_t)NTOT * C_;   // 50176*256
  unsigned short* rT = yT + (size_t)NTOT * C_;   // 50176*64
  unsigned short* tT = rT + (size_t)NTOT * RED_; // 50176*256
  unsigned short* w1b = tT + (size_t)NTOT * C_;
  unsigned short* redb = w1b + 65536;
  unsigned short* spanb = redb + 16384;
  unsigned short* w3b = spanb + 50176;
  float* out = (float*)d_out;
  (void)xT;

  dim3 blk(256);
  wconv<<<dim3(256), blk, 0, stream>>>(w1, red_w, span_w, w3, w1b, redb, spanb, w3b);
  // y_T = tanh(bn1(w1 @ x)) AND r_T = relu(bn_red(red_w @ y)); x-transpose fused
  gemm_yr<<<dim3(784), blk, 0, stream>>>(
      w1b, x, redb, b1, bn1g, bn1b, bn1m, bn1v,
      red_b, rbg, rbb, rbm, rbv, yT, rT);
  // t_T = tanh(bn2(involution(y; span(r))))  — span fused, 512-thread blocks
  gather_inv<<<dim3(16, 14, 16), dim3(512), 0, stream>>>(
      yT, rT, spanb, span_b, bn2g, bn2b, bn2m, bn2v, tT);
  // out = bn3(w3 @ t) + x  (planar fp32), dbuf-pipelined (v10 version)
  gemm_out<<<dim3(392, 2), blk, 0, stream>>>(
      w3b, tT, b3, bn3g, bn3b, bn3m, bn3v, x, out);
}